// Round 9
// baseline (189.677 us; speedup 1.0000x reference)
//
#include <hip/hip_runtime.h>
#include <stdint.h>

// ---------------------------------------------------------------------------
// PrimitiveFitting: voxel-hash primitive fitting (mu + scaled-eigvec R).
//
// R8 post-mortem: R7 bundle (active-range zero w/ prep dependency, singleton
// scattered output writes, +1 dispatch) cost ~12us vs R6. R9 = R6 structure
// (combined zero+minmax, acc-only drain, coalesced finalize) + ONE isolated
// feature: coarse bitmap (1bit/bm-word, 675KB L2-resident) filtering probe's
// random fine-bitmap loads. A/B vs R6=176.8us attributes coarse's value.
// ---------------------------------------------------------------------------

#define WMAX   5402624u       // bitmap words = 2638 * 2048  (>= 10*258^3 / 32)
#define PBLK   2638           // scan superblocks (2048 words = 65536 bits)
#define CHUNK  11             // ceil(PBLK / 256)
#define HCAP   1024           // LDS staging entries / block (expected ~280)
#define HITCAP 786432         // global hit list capacity (expected ~216k)
#define MMB    784            // zero+minmax blocks

struct Hdr {
  float pc_min[4];
  int   dims[4];
  int   M;
  int   sb_lo, sb_hi;         // active superblock range [lo, hi)
};

__device__ __forceinline__ unsigned fkey_map(float f) {
  unsigned u = __float_as_uint(f);
  return (u & 0x80000000u) ? ~u : (u | 0x80000000u);
}
__device__ __forceinline__ float fkey_unmap(unsigned u) {
  unsigned b = (u & 0x80000000u) ? (u ^ 0x80000000u) : ~u;
  return __uint_as_float(b);
}

__device__ __forceinline__ void coors_from(float4 p, float pc0, float pc1,
                                           float pc2, float pc3, int c[4]) {
  // Must match numpy bitwise: f32 subtract, IEEE f32 divide, rint (half-even).
  c[0] = (int)rintf((p.x - pc0) / 1.0f) + 1;
  c[1] = (int)rintf((p.y - pc1) / 0.4f) + 1;
  c[2] = (int)rintf((p.z - pc2) / 0.4f) + 1;
  c[3] = (int)rintf((p.w - pc3) / 0.4f) + 1;
}

__device__ __forceinline__ void direct_accum(float* __restrict__ acc, int r,
                                             float wgt, float4 p) {
  float* a = acc + (size_t)r * 12;
  atomicAdd((unsigned*)(a + 11), 2u);   // never counted as singleton
  atomicAdd(a + 0, wgt);
  atomicAdd(a + 1, wgt * p.x);
  atomicAdd(a + 2, wgt * p.y);
  atomicAdd(a + 3, wgt * p.z);
  atomicAdd(a + 4, wgt * p.w);
  atomicAdd(a + 5, wgt * p.y * p.y);
  atomicAdd(a + 6, wgt * p.y * p.z);
  atomicAdd(a + 7, wgt * p.y * p.w);
  atomicAdd(a + 8, wgt * p.z * p.z);
  atomicAdd(a + 9, wgt * p.z * p.w);
  atomicAdd(a + 10, wgt * p.w * p.w);
}

__device__ __forceinline__ void jacobi_out(float ws, float4 v0, float4 v1,
                                           float4 v2, float* mu_o, float* R_o) {
  float mu0 = v0.y / ws, mu1 = v0.z / ws, mu2 = v0.w / ws, mu3 = v1.x / ws;
  float A[3][3];
  A[0][0] = v1.y / ws - mu1 * mu1;
  A[0][1] = A[1][0] = v1.z / ws - mu1 * mu2;
  A[0][2] = A[2][0] = v1.w / ws - mu1 * mu3;
  A[1][1] = v2.x / ws - mu2 * mu2;
  A[1][2] = A[2][1] = v2.y / ws - mu2 * mu3;
  A[2][2] = v2.z / ws - mu3 * mu3;

  float V[3][3] = {{1.f, 0.f, 0.f}, {0.f, 1.f, 0.f}, {0.f, 0.f, 1.f}};
  for (int sweep = 0; sweep < 8; ++sweep) {
    #pragma unroll
    for (int pi = 0; pi < 3; ++pi) {
      int p = (pi == 2) ? 1 : 0;
      int q = (pi == 0) ? 1 : 2;
      float apq = A[p][q];
      if (apq == 0.0f) continue;
      float app = A[p][p], aqq = A[q][q];
      float theta = (aqq - app) / (2.0f * apq);
      float t = 1.0f / (fabsf(theta) + sqrtf(theta * theta + 1.0f));
      if (theta < 0.0f) t = -t;
      float cth = 1.0f / sqrtf(t * t + 1.0f);
      float sth = t * cth;
      A[p][p] = app - t * apq;
      A[q][q] = aqq + t * apq;
      A[p][q] = A[q][p] = 0.0f;
      int k = 3 - p - q;
      float akp = A[k][p], akq = A[k][q];
      A[k][p] = A[p][k] = cth * akp - sth * akq;
      A[k][q] = A[q][k] = sth * akp + cth * akq;
      #pragma unroll
      for (int r = 0; r < 3; ++r) {
        float vp = V[r][p], vq = V[r][q];
        V[r][p] = cth * vp - sth * vq;
        V[r][q] = sth * vp + cth * vq;
      }
    }
  }
  float a[3] = {fabsf(A[0][0]), fabsf(A[1][1]), fabsf(A[2][2])};
  int idx[3] = {0, 1, 2};
  if (a[idx[0]] < a[idx[1]]) { int t = idx[0]; idx[0] = idx[1]; idx[1] = t; }
  if (a[idx[1]] < a[idx[2]]) { int t = idx[1]; idx[1] = idx[2]; idx[2] = t; }
  if (a[idx[0]] < a[idx[1]]) { int t = idx[0]; idx[0] = idx[1]; idx[1] = t; }
  float S0 = fmaxf(sqrtf(a[idx[0]]), 1e-6f);
  float S1 = fmaxf(sqrtf(a[idx[1]]), 1e-6f);
  float S2 = fmaxf(sqrtf(a[idx[2]]), 1e-6f);
  float U[3][3];
  #pragma unroll
  for (int r = 0; r < 3; ++r) {
    U[r][0] = V[r][idx[0]];
    U[r][1] = V[r][idx[1]];
    U[r][2] = V[r][idx[2]];
  }
  float det = U[0][0] * (U[1][1] * U[2][2] - U[1][2] * U[2][1])
            - U[0][1] * (U[1][0] * U[2][2] - U[1][2] * U[2][0])
            + U[0][2] * (U[1][0] * U[2][1] - U[1][1] * U[2][0]);
  float f2 = (det < 0.0f) ? -1.0f : 1.0f;
  mu_o[0] = mu0; mu_o[1] = mu1; mu_o[2] = mu2; mu_o[3] = mu3;
  R_o[0] = U[0][0] * S0; R_o[1] = U[0][1] * S1; R_o[2] = U[0][2] * S2 * f2;
  R_o[3] = U[1][0] * S0; R_o[4] = U[1][1] * S1; R_o[5] = U[1][2] * S2 * f2;
  R_o[6] = U[2][0] * S0; R_o[7] = U[2][1] * S1; R_o[8] = U[2][2] * S2 * f2;
}

// zero bm/cb/acc/part/g_cnt + per-block minmax partials (one dispatch)
__global__ void k_zero_minmax(const float4* __restrict__ pts, int n,
                              unsigned* __restrict__ mmpart,
                              unsigned* __restrict__ bm,
                              unsigned char* __restrict__ cb,
                              float* __restrict__ acc,
                              unsigned* __restrict__ part,
                              unsigned* __restrict__ g_cnt) {
  __shared__ unsigned smem[4 * 8];
  const int gtid = blockIdx.x * 256 + threadIdx.x;
  const int gridT = gridDim.x * 256;

  uint4 z = {0u, 0u, 0u, 0u};
  uint4* bm4 = (uint4*)bm;
  for (int i = gtid; i < (int)(WMAX / 4); i += gridT) bm4[i] = z;
  uint4* cb4 = (uint4*)cb;
  for (int i = gtid; i < (int)(WMAX / 128); i += gridT) cb4[i] = z;
  uint4* acc4 = (uint4*)acc;
  int acc4n = n * 3;                          // n*12 floats / 4
  for (int i = gtid; i < acc4n; i += gridT) acc4[i] = z;
  for (int i = gtid; i < 4096; i += gridT) part[i] = 0u;
  if (gtid == 0) *g_cnt = 0u;

  float mn[4] = { INFINITY,  INFINITY,  INFINITY,  INFINITY};
  float mx[4] = {-INFINITY, -INFINITY, -INFINITY, -INFINITY};
  for (int i = gtid; i < n; i += gridT) {
    float4 p = pts[i];
    mn[0] = fminf(mn[0], p.x); mx[0] = fmaxf(mx[0], p.x);
    mn[1] = fminf(mn[1], p.y); mx[1] = fmaxf(mx[1], p.y);
    mn[2] = fminf(mn[2], p.z); mx[2] = fmaxf(mx[2], p.z);
    mn[3] = fminf(mn[3], p.w); mx[3] = fmaxf(mx[3], p.w);
  }
  #pragma unroll
  for (int off = 32; off > 0; off >>= 1) {
    #pragma unroll
    for (int c = 0; c < 4; ++c) {
      mn[c] = fminf(mn[c], __shfl_down(mn[c], off));
      mx[c] = fmaxf(mx[c], __shfl_down(mx[c], off));
    }
  }
  int wave = threadIdx.x >> 6;
  if ((threadIdx.x & 63) == 0) {
    #pragma unroll
    for (int c = 0; c < 4; ++c) {
      smem[wave * 8 + c]     = fkey_map(mn[c]);
      smem[wave * 8 + 4 + c] = fkey_map(mx[c]);
    }
  }
  __syncthreads();
  int t = threadIdx.x;
  if (t < 8) {
    unsigned u = smem[t];
    #pragma unroll
    for (int w = 1; w < 4; ++w)
      u = (t < 4) ? min(u, smem[w * 8 + t]) : max(u, smem[w * 8 + t]);
    mmpart[blockIdx.x * 8 + t] = u;
  }
}

__global__ void k_prep(const unsigned* __restrict__ mmpart, Hdr* h, int nb) {
  __shared__ unsigned s[256 * 8];
  int t = threadIdx.x;
  unsigned v[8];
  #pragma unroll
  for (int c = 0; c < 4; ++c) { v[c] = 0xFFFFFFFFu; v[4 + c] = 0u; }
  for (int b = t; b < nb; b += 256) {
    #pragma unroll
    for (int c = 0; c < 4; ++c) {
      v[c] = min(v[c], mmpart[b * 8 + c]);
      v[4 + c] = max(v[4 + c], mmpart[b * 8 + 4 + c]);
    }
  }
  #pragma unroll
  for (int c = 0; c < 8; ++c) s[t * 8 + c] = v[c];
  __syncthreads();
  for (int off = 128; off > 0; off >>= 1) {
    if (t < off) {
      #pragma unroll
      for (int c = 0; c < 4; ++c)
        s[t * 8 + c] = min(s[t * 8 + c], s[(t + off) * 8 + c]);
      #pragma unroll
      for (int c = 4; c < 8; ++c)
        s[t * 8 + c] = max(s[t * 8 + c], s[(t + off) * 8 + c]);
    }
    __syncthreads();
  }
  if (t == 0) {
    const float vs[4] = {1.0f, 0.4f, 0.4f, 0.4f};
    #pragma unroll
    for (int c = 0; c < 4; ++c) {
      float mn = fkey_unmap(s[c]);
      float mx = fkey_unmap(s[4 + c]);
      float pmin = mn - vs[c] * 2.0f;
      float pmax = mx + vs[c] * 2.0f;
      h->pc_min[c] = pmin;
      h->dims[c] = (int)rintf((pmax - pmin) / vs[c]) + 3;  // np.round half-even
    }
    // active key range (batch rows only) -> scanA early-exit
    float min0 = fkey_unmap(s[0]);
    float max0 = fkey_unmap(s[4]);
    int c0min = (int)rintf(min0 - h->pc_min[0]) + 1;
    int c0max = (int)rintf(max0 - h->pc_min[0]) + 1;
    long long D = (long long)h->dims[1] * h->dims[2] * h->dims[3];
    long long keylo = (long long)c0min * D;
    long long keyhi = (long long)(c0max + 1) * D;
    int sblo = 0, sbhi = PBLK;
    if (keylo >= 0 && keyhi <= (long long)WMAX * 32ll) {
      sblo = max(0, (int)((keylo >> 5) >> 11) - 1);
      sbhi = min((int)PBLK, (int)((((keyhi + 31) >> 5) + 2047) >> 11) + 1);
    }
    h->sb_lo = sblo;
    h->sb_hi = sbhi;
  }
}

__global__ void k_mark(const float4* __restrict__ pts, int n,
                       const Hdr* __restrict__ h, unsigned* __restrict__ bm) {
  int i = blockIdx.x * 256 + threadIdx.x;
  if (i >= n) return;
  float4 p = pts[i];
  int c[4];
  coors_from(p, h->pc_min[0], h->pc_min[1], h->pc_min[2], h->pc_min[3], c);
  int key = ((c[0] * h->dims[1] + c[1]) * h->dims[2] + c[2]) * h->dims[3] + c[3];
  unsigned uk = (unsigned)key;
  if (uk >= WMAX * 32u) return;   // safety (never taken for valid data)
  atomicOr(&bm[uk >> 5], 1u << (uk & 31u));
}

// active superblocks only; emits rank16 + coarse map + superblock totals.
__global__ void k_scanA(const unsigned* __restrict__ bm,
                        unsigned short* __restrict__ rank16,
                        unsigned char* __restrict__ cb,
                        unsigned* __restrict__ part,
                        const Hdr* __restrict__ h) {
  __shared__ unsigned s[256];
  int t = threadIdx.x;
  int vb = blockIdx.x;
  if (vb < h->sb_lo || vb >= h->sb_hi) return;   // inactive: stays zero
  size_t base = (size_t)vb * 2048 + (size_t)t * 8;
  uint4 a = *(const uint4*)(bm + base);
  uint4 b = *(const uint4*)(bm + base + 4);
  unsigned wv[8] = {a.x, a.y, a.z, a.w, b.x, b.y, b.z, b.w};
  unsigned pc[8], sum = 0, cbyte = 0;
  #pragma unroll
  for (int k = 0; k < 8; ++k) {
    pc[k] = (unsigned)__popc(wv[k]);
    sum += pc[k];
    cbyte |= (wv[k] != 0u ? 1u : 0u) << k;
  }
  cb[(size_t)vb * 256 + t] = (unsigned char)cbyte;
  s[t] = sum; __syncthreads();
  for (int off = 1; off < 256; off <<= 1) {
    unsigned v = (t >= off) ? s[t - off] : 0u;
    __syncthreads();
    s[t] += v;
    __syncthreads();
  }
  unsigned run = s[t] - sum;
  unsigned r[8];
  #pragma unroll
  for (int k = 0; k < 8; ++k) { r[k] = run; run += pc[k]; }
  uint4 o;
  o.x = (r[0] & 0xFFFFu) | (r[1] << 16);
  o.y = (r[2] & 0xFFFFu) | (r[3] << 16);
  o.z = (r[4] & 0xFFFFu) | (r[5] << 16);
  o.w = (r[6] & 0xFFFFu) | (r[7] << 16);
  *(uint4*)(rank16 + base) = o;
  if (t == 255) part[vb] = s[255];
}

// single block: exclusive scan of superblock totals.
__global__ void k_scanB(unsigned* __restrict__ part, Hdr* h) {
  __shared__ unsigned s[256];
  int t = threadIdx.x;
  int lo = t * CHUNK;
  unsigned local[CHUNK];
  unsigned sum = 0;
  #pragma unroll
  for (int k = 0; k < CHUNK; ++k) {
    int j = lo + k;
    local[k] = (j < PBLK) ? part[j] : 0u;
    sum += local[k];
  }
  s[t] = sum; __syncthreads();
  for (int off = 1; off < 256; off <<= 1) {
    unsigned v = (t >= off) ? s[t - off] : 0u;
    __syncthreads();
    s[t] += v;
    __syncthreads();
  }
  unsigned run = s[t] - sum;
  #pragma unroll
  for (int k = 0; k < CHUNK; ++k) {
    int j = lo + k;
    if (j < PBLK) part[j] = run;
    run += local[k];
  }
  if (t == 255) h->M = (int)s[255];
}

#define CBIT(x) ((cb[(x) >> 3] >> ((x) & 7u)) & 1u)

// 9 coarse-bit probes per point; fine bitmap touched only on coarse hits.
__global__ void k_probe(const float4* __restrict__ pts, int n,
                        const Hdr* __restrict__ h,
                        const unsigned* __restrict__ bm,
                        const unsigned char* __restrict__ cb,
                        const unsigned short* __restrict__ rank16,
                        const unsigned* __restrict__ part,
                        int* __restrict__ hit_i, int* __restrict__ hit_r,
                        float* __restrict__ hit_w,
                        unsigned* __restrict__ g_cnt,
                        float* __restrict__ acc) {
  __shared__ int s_cnt;
  __shared__ int s_base;
  __shared__ int   s_i[HCAP];
  __shared__ int   s_r[HCAP];
  __shared__ float s_w[HCAP];
  if (threadIdx.x == 0) s_cnt = 0;
  __syncthreads();
  int i = blockIdx.x * 256 + threadIdx.x;
  const float gg = 0.4f * 0.4f;
  const float decay2 = (gg + gg + gg) * 0.25f;   // bitwise == ref
  if (i < n) {
    float4 p = pts[i];
    int c[4];
    coors_from(p, h->pc_min[0], h->pc_min[1], h->pc_min[2], h->pc_min[3], c);
    int d1 = h->dims[1], d2 = h->dims[2], d3 = h->dims[3];
    float m1 = h->pc_min[1], m2 = h->pc_min[2], m3 = h->pc_min[3];
    #pragma unroll
    for (int dx = -1; dx <= 1; ++dx) {
      #pragma unroll
      for (int dy = -1; dy <= 1; ++dy) {
        int n1 = c[1] + dx, n2 = c[2] + dy;
        int kc = ((c[0] * d1 + n1) * d2 + n2) * d3 + c[3];  // dz = 0
        unsigned k = (unsigned)kc;
        if (k < 1u || k + 1u >= WMAX * 32u) continue;       // safety
        unsigned w = k >> 5, b = k & 31u;
        unsigned tri = 0;
        if (b != 0u && b != 31u) {
          if (CBIT(w)) tri = (bm[w] >> (b - 1)) & 7u;
        } else if (b == 0u) {
          unsigned t0 = CBIT(w - 1) ? (bm[w - 1] >> 31) : 0u;
          unsigned t1 = CBIT(w) ? ((bm[w] & 3u) << 1) : 0u;
          tri = t0 | t1;
        } else {
          unsigned t0 = CBIT(w) ? ((bm[w] >> 30) & 3u) : 0u;
          unsigned t1 = CBIT(w + 1) ? ((bm[w + 1] & 1u) << 2) : 0u;
          tri = t0 | t1;
        }
        if (!tri) continue;
        #pragma unroll
        for (int j = 0; j < 3; ++j) {
          if (!((tri >> j) & 1u)) continue;
          unsigned kj = k + (unsigned)(j - 1);
          unsigned wj = kj >> 5, bj = kj & 31u;
          unsigned word = bm[wj];               // L1-hot (loaded for tri)
          int r = (int)(part[kj >> 16] + (unsigned)rank16[wj] +
                        __popc(word & ((1u << bj) - 1u)));
          int n3 = c[3] + (j - 1);
          float cx = (float)(n1 - 1) * 0.4f + m1;
          float cy = (float)(n2 - 1) * 0.4f + m2;
          float cz = (float)(n3 - 1) * 0.4f + m3;
          float ex = p.y - cx, ey = p.z - cy, ez = p.w - cz;
          float dd = ex * ex + ey * ey + ez * ez;
          float wgt = expf(-dd / decay2);
          int pos = atomicAdd(&s_cnt, 1);
          if (pos < HCAP) {
            s_i[pos] = i; s_r[pos] = r; s_w[pos] = wgt;
          } else {
            direct_accum(acc, r, wgt, p);       // LDS overflow (rare)
          }
        }
      }
    }
  }
  __syncthreads();
  int cnt = min(s_cnt, HCAP);
  if (threadIdx.x == 0) s_base = (int)atomicAdd(g_cnt, (unsigned)cnt);
  __syncthreads();
  int base = s_base;
  for (int j = threadIdx.x; j < cnt; j += 256) {
    int gpos = base + j;
    int r = s_r[j];
    if (gpos < HITCAP) {
      hit_i[gpos] = s_i[j];
      hit_r[gpos] = r;
      hit_w[gpos] = s_w[j];
      atomicAdd((unsigned*)(acc + (size_t)r * 12 + 11), 1u);
    } else {
      direct_accum(acc, r, s_w[j], pts[s_i[j]]);  // overflow (rare)
    }
  }
}

// single-contributor voxels (~93%) -> three plain float4 stores into acc;
// shared voxels -> 11 atomicAdds. Outputs written (coalesced) by finalize.
__global__ void k_drain(const float4* __restrict__ pts,
                        const int* __restrict__ hit_i,
                        const int* __restrict__ hit_r,
                        const float* __restrict__ hit_w,
                        const unsigned* __restrict__ g_cnt,
                        float* __restrict__ acc) {
  int total = min((int)*g_cnt, HITCAP);
  for (int j = blockIdx.x * 256 + threadIdx.x; j < total;
       j += gridDim.x * 256) {
    int r = hit_r[j];
    float wgt = hit_w[j];
    float4 q = pts[hit_i[j]];
    float* a = acc + (size_t)r * 12;
    unsigned c = *(const unsigned*)(a + 11);
    if (c == 1u) {
      float4 v0 = {wgt, wgt * q.x, wgt * q.y, wgt * q.z};
      float4 v1 = {wgt * q.w, wgt * q.y * q.y, wgt * q.y * q.z,
                   wgt * q.y * q.w};
      float4 v2 = {wgt * q.z * q.z, wgt * q.z * q.w, wgt * q.w * q.w,
                   __uint_as_float(1u)};
      float4* av = (float4*)a;
      av[0] = v0; av[1] = v1; av[2] = v2;
    } else {
      atomicAdd(a + 0, wgt);
      atomicAdd(a + 1, wgt * q.x);
      atomicAdd(a + 2, wgt * q.y);
      atomicAdd(a + 3, wgt * q.z);
      atomicAdd(a + 4, wgt * q.w);
      atomicAdd(a + 5, wgt * q.y * q.y);
      atomicAdd(a + 6, wgt * q.y * q.z);
      atomicAdd(a + 7, wgt * q.y * q.w);
      atomicAdd(a + 8, wgt * q.z * q.z);
      atomicAdd(a + 9, wgt * q.z * q.w);
      atomicAdd(a + 10, wgt * q.w * q.w);
    }
  }
}

__global__ void k_finalize(const Hdr* __restrict__ h,
                           const float* __restrict__ acc,
                           float* __restrict__ out_mu,
                           float* __restrict__ out_R, int n) {
  int i = blockIdx.x * 256 + threadIdx.x;
  if (i >= n) return;
  float* mu_o = out_mu + (size_t)i * 4;
  float* R_o = out_R + (size_t)i * 9;
  if (i >= h->M) {                       // padding slots -> zeros
    mu_o[0] = mu_o[1] = mu_o[2] = mu_o[3] = 0.0f;
    #pragma unroll
    for (int k = 0; k < 9; ++k) R_o[k] = 0.0f;
    return;
  }
  const float4* av = (const float4*)(acc + (size_t)i * 12);
  float4 v0 = av[0], v1 = av[1], v2 = av[2];
  jacobi_out(v0.x, v0, v1, v2, mu_o, R_o);
}

// ============================================================================
extern "C" void kernel_launch(void* const* d_in, const int* in_sizes, int n_in,
                              void* d_out, int out_size, void* d_ws,
                              size_t ws_size, hipStream_t stream) {
  const float4* pts = (const float4*)d_in[0];
  int n = in_sizes[0] / 4;
  float* out = (float*)d_out;
  float* outR = out + (size_t)4 * n;

  char* ws = (char*)d_ws;
  Hdr* hdr = (Hdr*)ws;
  size_t off = 256;
  unsigned* mmpart = (unsigned*)(ws + off);      off += (size_t)MMB * 8 * 4;
  unsigned* bm = (unsigned*)(ws + off);          off += (size_t)WMAX * 4;
  unsigned short* rank16 = (unsigned short*)(ws + off); off += (size_t)WMAX * 2;
  unsigned char* cb = (unsigned char*)(ws + off); off += (size_t)(WMAX / 8) + 256;
  unsigned* part = (unsigned*)(ws + off);        off += 4096 * 4;
  unsigned* g_cnt = (unsigned*)(ws + off);       off += 256;
  int* hit_i = (int*)(ws + off);                 off += (size_t)HITCAP * 4;
  int* hit_r = (int*)(ws + off);                 off += (size_t)HITCAP * 4;
  float* hit_w = (float*)(ws + off);             off += (size_t)HITCAP * 4;
  float* acc = (float*)(ws + off);               // n * 12 floats
  size_t needed = off + (size_t)n * 12 * 4;
  if (ws_size < needed) return;

  int nb = (n + 255) / 256;
  k_zero_minmax<<<MMB, 256, 0, stream>>>(pts, n, mmpart, bm, cb, acc, part,
                                         g_cnt);
  k_prep<<<1, 256, 0, stream>>>(mmpart, hdr, MMB);
  k_mark<<<nb, 256, 0, stream>>>(pts, n, hdr, bm);
  k_scanA<<<PBLK, 256, 0, stream>>>(bm, rank16, cb, part, hdr);
  k_scanB<<<1, 256, 0, stream>>>(part, hdr);
  k_probe<<<nb, 256, 0, stream>>>(pts, n, hdr, bm, cb, rank16, part,
                                  hit_i, hit_r, hit_w, g_cnt, acc);
  k_drain<<<512, 256, 0, stream>>>(pts, hit_i, hit_r, hit_w, g_cnt, acc);
  k_finalize<<<nb, 256, 0, stream>>>(hdr, acc, out, outR, n);
}

// Round 10
// 161.343 us; speedup vs baseline: 1.1756x; 1.1756x over previous
//
#include <hip/hip_runtime.h>
#include <stdint.h>

// ---------------------------------------------------------------------------
// PrimitiveFitting: voxel-hash primitive fitting (mu + scaled-eigvec R).
//
// R9 post-mortem: (a) coarse bitmap = ~13us regression (dependent-load chain;
// fine bitmap already L2-absorbed) -> dropped, probe reverted to R6's 9-word
// form. (b) k_finalize ran with LDS_Block_Size=36864 + 84k bank conflicts:
// runtime-indexed private arrays (A[p][q], V[r][idx[k]]) were demoted to
// scratch/LDS. R10 Jacobi is fully static-indexed (explicit rotations,
// scalar conditional swaps) -> register-resident.
// ---------------------------------------------------------------------------

#define WMAX   5402624u       // bitmap words = 2638 * 2048  (>= 10*258^3 / 32)
#define PBLK   2638           // scan superblocks (2048 words = 65536 bits)
#define CHUNK  11             // ceil(PBLK / 256)
#define HCAP   1024           // LDS staging entries / block (expected ~280)
#define HITCAP 786432         // global hit list capacity (expected ~216k)
#define MMB    784            // zero+minmax blocks

struct Hdr {
  float pc_min[4];
  int   dims[4];
  int   M;
  int   sb_lo, sb_hi;         // active superblock range [lo, hi)
};

__device__ __forceinline__ unsigned fkey_map(float f) {
  unsigned u = __float_as_uint(f);
  return (u & 0x80000000u) ? ~u : (u | 0x80000000u);
}
__device__ __forceinline__ float fkey_unmap(unsigned u) {
  unsigned b = (u & 0x80000000u) ? (u ^ 0x80000000u) : ~u;
  return __uint_as_float(b);
}

__device__ __forceinline__ void coors_from(float4 p, float pc0, float pc1,
                                           float pc2, float pc3, int c[4]) {
  // Must match numpy bitwise: f32 subtract, IEEE f32 divide, rint (half-even).
  c[0] = (int)rintf((p.x - pc0) / 1.0f) + 1;
  c[1] = (int)rintf((p.y - pc1) / 0.4f) + 1;
  c[2] = (int)rintf((p.z - pc2) / 0.4f) + 1;
  c[3] = (int)rintf((p.w - pc3) / 0.4f) + 1;
}

__device__ __forceinline__ void direct_accum(float* __restrict__ acc, int r,
                                             float wgt, float4 p) {
  float* a = acc + (size_t)r * 12;
  atomicAdd((unsigned*)(a + 11), 2u);   // never counted as singleton
  atomicAdd(a + 0, wgt);
  atomicAdd(a + 1, wgt * p.x);
  atomicAdd(a + 2, wgt * p.y);
  atomicAdd(a + 3, wgt * p.z);
  atomicAdd(a + 4, wgt * p.w);
  atomicAdd(a + 5, wgt * p.y * p.y);
  atomicAdd(a + 6, wgt * p.y * p.z);
  atomicAdd(a + 7, wgt * p.y * p.w);
  atomicAdd(a + 8, wgt * p.z * p.z);
  atomicAdd(a + 9, wgt * p.z * p.w);
  atomicAdd(a + 10, wgt * p.w * p.w);
}

// one static Jacobi rotation on (p,q); k is the third index.
// app=A[p][p], aqq=A[q][q], apq=A[p][q], akp=A[k][p], akq=A[k][q];
// (vp*,vq*) are columns p and q of V.
__device__ __forceinline__ void jrot(float& app, float& aqq, float& apq,
                                     float& akp, float& akq,
                                     float& vp0, float& vp1, float& vp2,
                                     float& vq0, float& vq1, float& vq2) {
  float a = apq;
  if (a == 0.0f) return;
  float theta = (aqq - app) / (2.0f * a);
  float t = 1.0f / (fabsf(theta) + sqrtf(theta * theta + 1.0f));
  if (theta < 0.0f) t = -t;
  float c = 1.0f / sqrtf(t * t + 1.0f);
  float s = t * c;
  app -= t * a;
  aqq += t * a;
  apq = 0.0f;
  float kp = akp, kq = akq;
  akp = c * kp - s * kq;
  akq = s * kp + c * kq;
  float x, y;
  x = vp0; y = vq0; vp0 = c * x - s * y; vq0 = s * x + c * y;
  x = vp1; y = vq1; vp1 = c * x - s * y; vq1 = s * x + c * y;
  x = vp2; y = vq2; vp2 = c * x - s * y; vq2 = s * x + c * y;
}

// register-resident 3x3 symmetric eigensolver + output (no indexed arrays!)
__device__ __forceinline__ void jacobi_out(float ws, float4 v0, float4 v1,
                                           float4 v2, float* mu_o, float* R_o) {
  float mu0 = v0.y / ws, mu1 = v0.z / ws, mu2 = v0.w / ws, mu3 = v1.x / ws;
  float a00 = v1.y / ws - mu1 * mu1;
  float a01 = v1.z / ws - mu1 * mu2;
  float a02 = v1.w / ws - mu1 * mu3;
  float a11 = v2.x / ws - mu2 * mu2;
  float a12 = v2.y / ws - mu2 * mu3;
  float a22 = v2.z / ws - mu3 * mu3;

  float u00 = 1.f, u01 = 0.f, u02 = 0.f;
  float u10 = 0.f, u11 = 1.f, u12 = 0.f;
  float u20 = 0.f, u21 = 0.f, u22 = 1.f;
  #pragma unroll
  for (int sweep = 0; sweep < 8; ++sweep) {
    // (p,q)=(0,1), k=2: akp=A[2][0]=a02, akq=A[2][1]=a12; cols 0,1
    jrot(a00, a11, a01, a02, a12, u00, u10, u20, u01, u11, u21);
    // (p,q)=(0,2), k=1: akp=A[1][0]=a01, akq=A[1][2]=a12; cols 0,2
    jrot(a00, a22, a02, a01, a12, u00, u10, u20, u02, u12, u22);
    // (p,q)=(1,2), k=0: akp=A[0][1]=a01, akq=A[0][2]=a02; cols 1,2
    jrot(a11, a22, a12, a01, a02, u01, u11, u21, u02, u12, u22);
  }
  float l0 = fabsf(a00), l1 = fabsf(a11), l2 = fabsf(a22);
  // sort columns by |lambda| descending via scalar swaps (register-resident)
  float t;
  if (l0 < l1) {
    t = l0; l0 = l1; l1 = t;
    t = u00; u00 = u01; u01 = t;
    t = u10; u10 = u11; u11 = t;
    t = u20; u20 = u21; u21 = t;
  }
  if (l1 < l2) {
    t = l1; l1 = l2; l2 = t;
    t = u01; u01 = u02; u02 = t;
    t = u11; u11 = u12; u12 = t;
    t = u21; u21 = u22; u22 = t;
  }
  if (l0 < l1) {
    t = l0; l0 = l1; l1 = t;
    t = u00; u00 = u01; u01 = t;
    t = u10; u10 = u11; u11 = t;
    t = u20; u20 = u21; u21 = t;
  }
  float S0 = fmaxf(sqrtf(l0), 1e-6f);
  float S1 = fmaxf(sqrtf(l1), 1e-6f);
  float S2 = fmaxf(sqrtf(l2), 1e-6f);
  float det = u00 * (u11 * u22 - u12 * u21)
            - u01 * (u10 * u22 - u12 * u20)
            + u02 * (u10 * u21 - u11 * u20);
  float f2 = (det < 0.0f) ? -S2 : S2;
  mu_o[0] = mu0; mu_o[1] = mu1; mu_o[2] = mu2; mu_o[3] = mu3;
  R_o[0] = u00 * S0; R_o[1] = u01 * S1; R_o[2] = u02 * f2;
  R_o[3] = u10 * S0; R_o[4] = u11 * S1; R_o[5] = u12 * f2;
  R_o[6] = u20 * S0; R_o[7] = u21 * S1; R_o[8] = u22 * f2;
}

// zero bm/acc/part/g_cnt + per-block minmax partials (one dispatch)
__global__ void k_zero_minmax(const float4* __restrict__ pts, int n,
                              unsigned* __restrict__ mmpart,
                              unsigned* __restrict__ bm,
                              float* __restrict__ acc,
                              unsigned* __restrict__ part,
                              unsigned* __restrict__ g_cnt) {
  __shared__ unsigned smem[4 * 8];
  const int gtid = blockIdx.x * 256 + threadIdx.x;
  const int gridT = gridDim.x * 256;

  uint4 z = {0u, 0u, 0u, 0u};
  uint4* bm4 = (uint4*)bm;
  for (int i = gtid; i < (int)(WMAX / 4); i += gridT) bm4[i] = z;
  uint4* acc4 = (uint4*)acc;
  int acc4n = n * 3;                          // n*12 floats / 4
  for (int i = gtid; i < acc4n; i += gridT) acc4[i] = z;
  for (int i = gtid; i < 4096; i += gridT) part[i] = 0u;
  if (gtid == 0) *g_cnt = 0u;

  float mn[4] = { INFINITY,  INFINITY,  INFINITY,  INFINITY};
  float mx[4] = {-INFINITY, -INFINITY, -INFINITY, -INFINITY};
  for (int i = gtid; i < n; i += gridT) {
    float4 p = pts[i];
    mn[0] = fminf(mn[0], p.x); mx[0] = fmaxf(mx[0], p.x);
    mn[1] = fminf(mn[1], p.y); mx[1] = fmaxf(mx[1], p.y);
    mn[2] = fminf(mn[2], p.z); mx[2] = fmaxf(mx[2], p.z);
    mn[3] = fminf(mn[3], p.w); mx[3] = fmaxf(mx[3], p.w);
  }
  #pragma unroll
  for (int off = 32; off > 0; off >>= 1) {
    #pragma unroll
    for (int c = 0; c < 4; ++c) {
      mn[c] = fminf(mn[c], __shfl_down(mn[c], off));
      mx[c] = fmaxf(mx[c], __shfl_down(mx[c], off));
    }
  }
  int wave = threadIdx.x >> 6;
  if ((threadIdx.x & 63) == 0) {
    #pragma unroll
    for (int c = 0; c < 4; ++c) {
      smem[wave * 8 + c]     = fkey_map(mn[c]);
      smem[wave * 8 + 4 + c] = fkey_map(mx[c]);
    }
  }
  __syncthreads();
  int t = threadIdx.x;
  if (t < 8) {
    unsigned u = smem[t];
    #pragma unroll
    for (int w = 1; w < 4; ++w)
      u = (t < 4) ? min(u, smem[w * 8 + t]) : max(u, smem[w * 8 + t]);
    mmpart[blockIdx.x * 8 + t] = u;
  }
}

__global__ void k_prep(const unsigned* __restrict__ mmpart, Hdr* h, int nb) {
  __shared__ unsigned s[256 * 8];
  int t = threadIdx.x;
  unsigned v[8];
  #pragma unroll
  for (int c = 0; c < 4; ++c) { v[c] = 0xFFFFFFFFu; v[4 + c] = 0u; }
  for (int b = t; b < nb; b += 256) {
    #pragma unroll
    for (int c = 0; c < 4; ++c) {
      v[c] = min(v[c], mmpart[b * 8 + c]);
      v[4 + c] = max(v[4 + c], mmpart[b * 8 + 4 + c]);
    }
  }
  #pragma unroll
  for (int c = 0; c < 8; ++c) s[t * 8 + c] = v[c];
  __syncthreads();
  for (int off = 128; off > 0; off >>= 1) {
    if (t < off) {
      #pragma unroll
      for (int c = 0; c < 4; ++c)
        s[t * 8 + c] = min(s[t * 8 + c], s[(t + off) * 8 + c]);
      #pragma unroll
      for (int c = 4; c < 8; ++c)
        s[t * 8 + c] = max(s[t * 8 + c], s[(t + off) * 8 + c]);
    }
    __syncthreads();
  }
  if (t == 0) {
    const float vs[4] = {1.0f, 0.4f, 0.4f, 0.4f};
    #pragma unroll
    for (int c = 0; c < 4; ++c) {
      float mn = fkey_unmap(s[c]);
      float mx = fkey_unmap(s[4 + c]);
      float pmin = mn - vs[c] * 2.0f;
      float pmax = mx + vs[c] * 2.0f;
      h->pc_min[c] = pmin;
      h->dims[c] = (int)rintf((pmax - pmin) / vs[c]) + 3;  // np.round half-even
    }
    // active key range (batch rows only) -> scanA early-exit
    float min0 = fkey_unmap(s[0]);
    float max0 = fkey_unmap(s[4]);
    int c0min = (int)rintf(min0 - h->pc_min[0]) + 1;
    int c0max = (int)rintf(max0 - h->pc_min[0]) + 1;
    long long D = (long long)h->dims[1] * h->dims[2] * h->dims[3];
    long long keylo = (long long)c0min * D;
    long long keyhi = (long long)(c0max + 1) * D;
    int sblo = 0, sbhi = PBLK;
    if (keylo >= 0 && keyhi <= (long long)WMAX * 32ll) {
      sblo = max(0, (int)((keylo >> 5) >> 11) - 1);
      sbhi = min((int)PBLK, (int)((((keyhi + 31) >> 5) + 2047) >> 11) + 1);
    }
    h->sb_lo = sblo;
    h->sb_hi = sbhi;
  }
}

__global__ void k_mark(const float4* __restrict__ pts, int n,
                       const Hdr* __restrict__ h, unsigned* __restrict__ bm) {
  int i = blockIdx.x * 256 + threadIdx.x;
  if (i >= n) return;
  float4 p = pts[i];
  int c[4];
  coors_from(p, h->pc_min[0], h->pc_min[1], h->pc_min[2], h->pc_min[3], c);
  int key = ((c[0] * h->dims[1] + c[1]) * h->dims[2] + c[2]) * h->dims[3] + c[3];
  unsigned uk = (unsigned)key;
  if (uk >= WMAX * 32u) return;   // safety (never taken for valid data)
  atomicOr(&bm[uk >> 5], 1u << (uk & 31u));
}

// active superblocks only; emits rank16 + superblock totals.
__global__ void k_scanA(const unsigned* __restrict__ bm,
                        unsigned short* __restrict__ rank16,
                        unsigned* __restrict__ part,
                        const Hdr* __restrict__ h) {
  __shared__ unsigned s[256];
  int t = threadIdx.x;
  int vb = blockIdx.x;
  if (vb < h->sb_lo || vb >= h->sb_hi) return;   // inactive: stays zero
  size_t base = (size_t)vb * 2048 + (size_t)t * 8;
  uint4 a = *(const uint4*)(bm + base);
  uint4 b = *(const uint4*)(bm + base + 4);
  unsigned pc[8] = {(unsigned)__popc(a.x), (unsigned)__popc(a.y),
                    (unsigned)__popc(a.z), (unsigned)__popc(a.w),
                    (unsigned)__popc(b.x), (unsigned)__popc(b.y),
                    (unsigned)__popc(b.z), (unsigned)__popc(b.w)};
  unsigned sum = 0;
  #pragma unroll
  for (int k = 0; k < 8; ++k) sum += pc[k];
  s[t] = sum; __syncthreads();
  for (int off = 1; off < 256; off <<= 1) {
    unsigned v = (t >= off) ? s[t - off] : 0u;
    __syncthreads();
    s[t] += v;
    __syncthreads();
  }
  unsigned run = s[t] - sum;
  unsigned r[8];
  #pragma unroll
  for (int k = 0; k < 8; ++k) { r[k] = run; run += pc[k]; }
  uint4 o;
  o.x = (r[0] & 0xFFFFu) | (r[1] << 16);
  o.y = (r[2] & 0xFFFFu) | (r[3] << 16);
  o.z = (r[4] & 0xFFFFu) | (r[5] << 16);
  o.w = (r[6] & 0xFFFFu) | (r[7] << 16);
  *(uint4*)(rank16 + base) = o;
  if (t == 255) part[vb] = s[255];
}

// single block: exclusive scan of superblock totals.
__global__ void k_scanB(unsigned* __restrict__ part, Hdr* h) {
  __shared__ unsigned s[256];
  int t = threadIdx.x;
  int lo = t * CHUNK;
  unsigned local[CHUNK];
  unsigned sum = 0;
  #pragma unroll
  for (int k = 0; k < CHUNK; ++k) {
    int j = lo + k;
    local[k] = (j < PBLK) ? part[j] : 0u;
    sum += local[k];
  }
  s[t] = sum; __syncthreads();
  for (int off = 1; off < 256; off <<= 1) {
    unsigned v = (t >= off) ? s[t - off] : 0u;
    __syncthreads();
    s[t] += v;
    __syncthreads();
  }
  unsigned run = s[t] - sum;
  #pragma unroll
  for (int k = 0; k < CHUNK; ++k) {
    int j = lo + k;
    if (j < PBLK) part[j] = run;
    run += local[k];
  }
  if (t == 255) h->M = (int)s[255];
}

// 9 word-probes per point (dz-triple = 3 consecutive bits); append hits
// (i,r,w) to global list + one count-atomic per hit.
__global__ void k_probe(const float4* __restrict__ pts, int n,
                        const Hdr* __restrict__ h,
                        const unsigned* __restrict__ bm,
                        const unsigned short* __restrict__ rank16,
                        const unsigned* __restrict__ part,
                        int* __restrict__ hit_i, int* __restrict__ hit_r,
                        float* __restrict__ hit_w,
                        unsigned* __restrict__ g_cnt,
                        float* __restrict__ acc) {
  __shared__ int s_cnt;
  __shared__ int s_base;
  __shared__ int   s_i[HCAP];
  __shared__ int   s_r[HCAP];
  __shared__ float s_w[HCAP];
  if (threadIdx.x == 0) s_cnt = 0;
  __syncthreads();
  int i = blockIdx.x * 256 + threadIdx.x;
  const float gg = 0.4f * 0.4f;
  const float decay2 = (gg + gg + gg) * 0.25f;   // bitwise == ref
  if (i < n) {
    float4 p = pts[i];
    int c[4];
    coors_from(p, h->pc_min[0], h->pc_min[1], h->pc_min[2], h->pc_min[3], c);
    int d1 = h->dims[1], d2 = h->dims[2], d3 = h->dims[3];
    float m1 = h->pc_min[1], m2 = h->pc_min[2], m3 = h->pc_min[3];
    #pragma unroll
    for (int dx = -1; dx <= 1; ++dx) {
      #pragma unroll
      for (int dy = -1; dy <= 1; ++dy) {
        int n1 = c[1] + dx, n2 = c[2] + dy;
        int kc = ((c[0] * d1 + n1) * d2 + n2) * d3 + c[3];  // dz = 0
        unsigned k = (unsigned)kc;
        if (k < 1u || k + 1u >= WMAX * 32u) continue;       // safety
        unsigned w = k >> 5, b = k & 31u;
        unsigned cur = bm[w];
        unsigned tri;
        if (b == 0u)
          tri = (bm[w - 1] >> 31) | ((cur & 3u) << 1);
        else if (b == 31u)
          tri = ((cur >> 30) & 3u) | ((bm[w + 1] & 1u) << 2);
        else
          tri = (cur >> (b - 1)) & 7u;
        if (!tri) continue;
        #pragma unroll
        for (int j = 0; j < 3; ++j) {
          if (!((tri >> j) & 1u)) continue;
          unsigned kj = k + (unsigned)(j - 1);
          unsigned wj = kj >> 5, bj = kj & 31u;
          unsigned word = (wj == w) ? cur : bm[wj];
          int r = (int)(part[kj >> 16] + (unsigned)rank16[wj] +
                        __popc(word & ((1u << bj) - 1u)));
          int n3 = c[3] + (j - 1);
          float cx = (float)(n1 - 1) * 0.4f + m1;
          float cy = (float)(n2 - 1) * 0.4f + m2;
          float cz = (float)(n3 - 1) * 0.4f + m3;
          float ex = p.y - cx, ey = p.z - cy, ez = p.w - cz;
          float dd = ex * ex + ey * ey + ez * ez;
          float wgt = expf(-dd / decay2);
          int pos = atomicAdd(&s_cnt, 1);
          if (pos < HCAP) {
            s_i[pos] = i; s_r[pos] = r; s_w[pos] = wgt;
          } else {
            direct_accum(acc, r, wgt, p);       // LDS overflow (rare)
          }
        }
      }
    }
  }
  __syncthreads();
  int cnt = min(s_cnt, HCAP);
  if (threadIdx.x == 0) s_base = (int)atomicAdd(g_cnt, (unsigned)cnt);
  __syncthreads();
  int base = s_base;
  for (int j = threadIdx.x; j < cnt; j += 256) {
    int gpos = base + j;
    int r = s_r[j];
    if (gpos < HITCAP) {
      hit_i[gpos] = s_i[j];
      hit_r[gpos] = r;
      hit_w[gpos] = s_w[j];
      atomicAdd((unsigned*)(acc + (size_t)r * 12 + 11), 1u);
    } else {
      direct_accum(acc, r, s_w[j], pts[s_i[j]]);  // overflow (rare)
    }
  }
}

// single-contributor voxels (~93%) -> three plain float4 stores into acc;
// shared voxels -> 11 atomicAdds. Outputs written (coalesced) by finalize.
__global__ void k_drain(const float4* __restrict__ pts,
                        const int* __restrict__ hit_i,
                        const int* __restrict__ hit_r,
                        const float* __restrict__ hit_w,
                        const unsigned* __restrict__ g_cnt,
                        float* __restrict__ acc) {
  int total = min((int)*g_cnt, HITCAP);
  for (int j = blockIdx.x * 256 + threadIdx.x; j < total;
       j += gridDim.x * 256) {
    int r = hit_r[j];
    float wgt = hit_w[j];
    float4 q = pts[hit_i[j]];
    float* a = acc + (size_t)r * 12;
    unsigned c = *(const unsigned*)(a + 11);
    if (c == 1u) {
      float4 v0 = {wgt, wgt * q.x, wgt * q.y, wgt * q.z};
      float4 v1 = {wgt * q.w, wgt * q.y * q.y, wgt * q.y * q.z,
                   wgt * q.y * q.w};
      float4 v2 = {wgt * q.z * q.z, wgt * q.z * q.w, wgt * q.w * q.w,
                   __uint_as_float(1u)};
      float4* av = (float4*)a;
      av[0] = v0; av[1] = v1; av[2] = v2;
    } else {
      atomicAdd(a + 0, wgt);
      atomicAdd(a + 1, wgt * q.x);
      atomicAdd(a + 2, wgt * q.y);
      atomicAdd(a + 3, wgt * q.z);
      atomicAdd(a + 4, wgt * q.w);
      atomicAdd(a + 5, wgt * q.y * q.y);
      atomicAdd(a + 6, wgt * q.y * q.z);
      atomicAdd(a + 7, wgt * q.y * q.w);
      atomicAdd(a + 8, wgt * q.z * q.z);
      atomicAdd(a + 9, wgt * q.z * q.w);
      atomicAdd(a + 10, wgt * q.w * q.w);
    }
  }
}

__global__ void k_finalize(const Hdr* __restrict__ h,
                           const float* __restrict__ acc,
                           float* __restrict__ out_mu,
                           float* __restrict__ out_R, int n) {
  int i = blockIdx.x * 256 + threadIdx.x;
  if (i >= n) return;
  float* mu_o = out_mu + (size_t)i * 4;
  float* R_o = out_R + (size_t)i * 9;
  if (i >= h->M) {                       // padding slots -> zeros
    mu_o[0] = mu_o[1] = mu_o[2] = mu_o[3] = 0.0f;
    #pragma unroll
    for (int k = 0; k < 9; ++k) R_o[k] = 0.0f;
    return;
  }
  const float4* av = (const float4*)(acc + (size_t)i * 12);
  float4 v0 = av[0], v1 = av[1], v2 = av[2];
  jacobi_out(v0.x, v0, v1, v2, mu_o, R_o);
}

// ============================================================================
extern "C" void kernel_launch(void* const* d_in, const int* in_sizes, int n_in,
                              void* d_out, int out_size, void* d_ws,
                              size_t ws_size, hipStream_t stream) {
  const float4* pts = (const float4*)d_in[0];
  int n = in_sizes[0] / 4;
  float* out = (float*)d_out;
  float* outR = out + (size_t)4 * n;

  char* ws = (char*)d_ws;
  Hdr* hdr = (Hdr*)ws;
  size_t off = 256;
  unsigned* mmpart = (unsigned*)(ws + off);      off += (size_t)MMB * 8 * 4;
  unsigned* bm = (unsigned*)(ws + off);          off += (size_t)WMAX * 4;
  unsigned short* rank16 = (unsigned short*)(ws + off); off += (size_t)WMAX * 2;
  unsigned* part = (unsigned*)(ws + off);        off += 4096 * 4;
  unsigned* g_cnt = (unsigned*)(ws + off);       off += 256;
  int* hit_i = (int*)(ws + off);                 off += (size_t)HITCAP * 4;
  int* hit_r = (int*)(ws + off);                 off += (size_t)HITCAP * 4;
  float* hit_w = (float*)(ws + off);             off += (size_t)HITCAP * 4;
  float* acc = (float*)(ws + off);               // n * 12 floats
  size_t needed = off + (size_t)n * 12 * 4;
  if (ws_size < needed) return;

  int nb = (n + 255) / 256;
  k_zero_minmax<<<MMB, 256, 0, stream>>>(pts, n, mmpart, bm, acc, part, g_cnt);
  k_prep<<<1, 256, 0, stream>>>(mmpart, hdr, MMB);
  k_mark<<<nb, 256, 0, stream>>>(pts, n, hdr, bm);
  k_scanA<<<PBLK, 256, 0, stream>>>(bm, rank16, part, hdr);
  k_scanB<<<1, 256, 0, stream>>>(part, hdr);
  k_probe<<<nb, 256, 0, stream>>>(pts, n, hdr, bm, rank16, part,
                                  hit_i, hit_r, hit_w, g_cnt, acc);
  k_drain<<<512, 256, 0, stream>>>(pts, hit_i, hit_r, hit_w, g_cnt, acc);
  k_finalize<<<nb, 256, 0, stream>>>(hdr, acc, out, outR, n);
}